// Round 9
// baseline (268.356 us; speedup 1.0000x reference)
//
#include <hip/hip_runtime.h>
#include <hip/hip_bf16.h>
#include <hip/hip_fp16.h>

#define B_ 8
#define N_ 2048
#define ALPHA_ 0.2f
#define LOG2E_ 1.44269504088896f

// Workspace offsets (~8.7 MB)
#define OFF_WB    0u         // 65536  : Wb f16 [B][64 o][64 i]
#define OFF_WA1   65536u     // 2048   : Wa1 f32 [B][64]
#define OFF_WA2   67584u     // 2048   : Wa2 f32 [B][64]
#define OFF_WH1   69632u     // 65536  : wh1 [B][N] f32 (log2e-scaled)
#define OFF_WH2   135168u    // 65536  : wh2 [B][N] f32 (log2e-scaled)
#define OFF_AB    200704u    // 131072 : float2 [B][N] = (A4=1/den, B4)
#define OFF_CNT   331776u    // 256    : atomic tickets [B*8]
#define OFF_DP    332032u    // 2097152: den partials f32 [32][B][N]
#define OFF_WHBT  2429184u   // 2097152: WhbT f16 [B][64 o][N]
#define OFF_MASK  4526336u   // 4194304: maskQ u64 [B][8 jg][N i][4 q]
                             //   bit t of (b,jg,i,q) = adj[b][i][jg*256+4t+q] > 0

typedef _Float16 half8_t __attribute__((ext_vector_type(8)));
typedef float f32x4_t __attribute__((ext_vector_type(4)));
union UH { unsigned u[4]; half8_t s; };

__device__ __forceinline__ unsigned pkh(float a, float b) {
  __half2 h = __floats2half2_rn(a, b);
  return *(unsigned*)&h;
}

// K1: W row r=(i,o): W=|state.Wp_w[r]+b|; emit Wb f16 [o][i], Wa1, Wa2
__global__ __launch_bounds__(256) void k1_hyperw(
    const float* __restrict__ state, const float* __restrict__ Wpw,
    const float* __restrict__ Wpb, const float* __restrict__ av,
    unsigned short* __restrict__ Wb, float* __restrict__ Wa1,
    float* __restrict__ Wa2) {
  int b = blockIdx.y;
  int r = blockIdx.x * 256 + threadIdx.x;
  int lane = threadIdx.x & 63;
  int i = r >> 6, o = r & 63;
  __shared__ float st[128];
  if (threadIdx.x < 128) st[threadIdx.x] = state[b * 128 + threadIdx.x];
  __syncthreads();
  float acc = Wpb[r];
  const float4* wp = (const float4*)(Wpw + (size_t)r * 128);
  #pragma unroll 8
  for (int hh = 0; hh < 32; ++hh) {
    float4 v = wp[hh];
    acc += st[hh*4]*v.x + st[hh*4+1]*v.y + st[hh*4+2]*v.z + st[hh*4+3]*v.w;
  }
  float wv = fabsf(acc);
  __half hw = __float2half(wv);
  Wb[b * 4096 + o * 64 + i] = *(unsigned short*)&hw;
  float p1 = wv * av[lane];
  float p2 = wv * av[64 + lane];
  #pragma unroll
  for (int off = 32; off > 0; off >>= 1) {
    p1 += __shfl_xor(p1, off);
    p2 += __shfl_xor(p2, off);
  }
  if (lane == 0) { Wa1[b * 64 + i] = p1; Wa2[b * 64 + i] = p2; }
}

// K2: WhbT via f16 MFMA (h @ W); wh1/wh2 via f32 dots — no LDS/barriers
__global__ __launch_bounds__(256) void k2_wh(
    const float* __restrict__ h, const unsigned short* __restrict__ Wb,
    const float* __restrict__ Wa1, const float* __restrict__ Wa2,
    float* __restrict__ Wh1, float* __restrict__ Wh2,
    unsigned short* __restrict__ WhbT) {
  int b = blockIdx.y;
  int tid = threadIdx.x, lane = tid & 63, w = tid >> 6;
  int n0 = blockIdx.x * 64 + w * 16;
  int l15 = lane & 15, kg = lane >> 4;
  int row = n0 + l15;
  const float* hrow = h + (((size_t)b * N_ + row) << 6);
  float4 ha0 = *(const float4*)(hrow + kg * 8);
  float4 ha1 = *(const float4*)(hrow + kg * 8 + 4);
  float4 hb0 = *(const float4*)(hrow + 32 + kg * 8);
  float4 hb1 = *(const float4*)(hrow + 32 + kg * 8 + 4);
  const float* wa1 = Wa1 + b * 64;
  const float* wa2 = Wa2 + b * 64;
  float4 A0 = *(const float4*)(wa1 + kg * 8),      A1 = *(const float4*)(wa1 + kg * 8 + 4);
  float4 A2 = *(const float4*)(wa1 + 32 + kg * 8), A3 = *(const float4*)(wa1 + 32 + kg * 8 + 4);
  float4 C0 = *(const float4*)(wa2 + kg * 8),      C1 = *(const float4*)(wa2 + kg * 8 + 4);
  float4 C2 = *(const float4*)(wa2 + 32 + kg * 8), C3 = *(const float4*)(wa2 + 32 + kg * 8 + 4);
  float v1 = ha0.x*A0.x + ha0.y*A0.y + ha0.z*A0.z + ha0.w*A0.w
           + ha1.x*A1.x + ha1.y*A1.y + ha1.z*A1.z + ha1.w*A1.w
           + hb0.x*A2.x + hb0.y*A2.y + hb0.z*A2.z + hb0.w*A2.w
           + hb1.x*A3.x + hb1.y*A3.y + hb1.z*A3.z + hb1.w*A3.w;
  float v2 = ha0.x*C0.x + ha0.y*C0.y + ha0.z*C0.z + ha0.w*C0.w
           + ha1.x*C1.x + ha1.y*C1.y + ha1.z*C1.z + ha1.w*C1.w
           + hb0.x*C2.x + hb0.y*C2.y + hb0.z*C2.z + hb0.w*C2.w
           + hb1.x*C3.x + hb1.y*C3.y + hb1.z*C3.z + hb1.w*C3.w;
  v1 += __shfl_xor(v1, 16); v1 += __shfl_xor(v1, 32);
  v2 += __shfl_xor(v2, 16); v2 += __shfl_xor(v2, 32);
  if (lane < 16) {
    Wh1[b * N_ + row] = v1 * LOG2E_;
    Wh2[b * N_ + row] = v2 * LOG2E_;
  }
  UH ua, ub;
  ua.u[0] = pkh(ha0.x, ha0.y); ua.u[1] = pkh(ha0.z, ha0.w);
  ua.u[2] = pkh(ha1.x, ha1.y); ua.u[3] = pkh(ha1.z, ha1.w);
  ub.u[0] = pkh(hb0.x, hb0.y); ub.u[1] = pkh(hb0.z, hb0.w);
  ub.u[2] = pkh(hb1.x, hb1.y); ub.u[3] = pkh(hb1.z, hb1.w);
  const unsigned short* wbb = Wb + b * 4096;
  f32x4_t acc[4];
  #pragma unroll
  for (int of = 0; of < 4; ++of) acc[of] = {0.f, 0.f, 0.f, 0.f};
  #pragma unroll
  for (int of = 0; of < 4; ++of) {
    int o = of * 16 + l15;
    half8_t b0 = *(const half8_t*)(wbb + o * 64 + kg * 8);
    half8_t b1 = *(const half8_t*)(wbb + o * 64 + 32 + kg * 8);
    acc[of] = __builtin_amdgcn_mfma_f32_16x16x32_f16(ua.s, b0, acc[of], 0, 0, 0);
    acc[of] = __builtin_amdgcn_mfma_f32_16x16x32_f16(ub.s, b1, acc[of], 0, 0, 0);
  }
  int nb = n0 + (kg << 2);
  #pragma unroll
  for (int of = 0; of < 4; ++of) {
    int o = of * 16 + l15;
    uint2 pk;
    pk.x = pkh(acc[of][0], acc[of][1]);
    pk.y = pkh(acc[of][2], acc[of][3]);
    *(uint2*)(WhbT + ((size_t)(b * 64 + o)) * N_ + nb) = pk;
  }
}

// K3: pack ballots + exp-free den accumulation; last block per (b,jg) reduces
// the 32 partials and writes ab (fused k3e via atomic ticket).
#define K3_PROC(VV, UVV, II)                                                 \
  do {                                                                       \
    bool p0 = (VV).x > 0, p1 = (VV).y > 0, p2 = (VV).z > 0, p3 = (VV).w > 0; \
    unsigned long long b0 = __ballot(p0), b1 = __ballot(p1);                 \
    unsigned long long b2 = __ballot(p2), b3 = __ballot(p3);                 \
    unsigned long long bsel = qsel == 0 ? b0 : qsel == 1 ? b1                \
                            : qsel == 2 ? b2 : b3;                           \
    wreg = (rsel == (II)) ? bsel : wreg;                                     \
    den0 += p0 ? fmaxf((UVV).x, (UVV).y * b2c0) : 0.f;                       \
    den1 += p1 ? fmaxf((UVV).x, (UVV).y * b2c1) : 0.f;                       \
    den2 += p2 ? fmaxf((UVV).x, (UVV).y * b2c2) : 0.f;                       \
    den3 += p3 ? fmaxf((UVV).x, (UVV).y * b2c3) : 0.f;                       \
  } while (0)

__global__ __launch_bounds__(256) void k3_mask(
    const int* __restrict__ adj, const float* __restrict__ Wh1,
    const float* __restrict__ Wh2, float* __restrict__ dp,
    unsigned long long* __restrict__ maskQ, int* __restrict__ cnt,
    float2* __restrict__ ab) {
  int jg = blockIdx.x, ic = blockIdx.y, b = blockIdx.z;  // 8 x 32 x 8
  int tid = threadIdx.x, lane = tid & 63, w = tid >> 6;
  int i0 = ic * 64 + w * 16;
  __shared__ float2 uvs[64];
  __shared__ float red[4][256];
  __shared__ int tickS;
  if (tid < 64) {
    float w1v = Wh1[b * N_ + ic * 64 + tid];
    uvs[tid] = make_float2(exp2f(w1v), exp2f(0.2f * w1v));
  }
  __syncthreads();
  float2 uv0 = uvs[(w<<4)+0],  uv1 = uvs[(w<<4)+1],  uv2 = uvs[(w<<4)+2],  uv3 = uvs[(w<<4)+3];
  float2 uv4 = uvs[(w<<4)+4],  uv5 = uvs[(w<<4)+5],  uv6 = uvs[(w<<4)+6],  uv7 = uvs[(w<<4)+7];
  float2 uv8 = uvs[(w<<4)+8],  uv9 = uvs[(w<<4)+9],  uvA = uvs[(w<<4)+10], uvB = uvs[(w<<4)+11];
  float2 uvC = uvs[(w<<4)+12], uvD = uvs[(w<<4)+13], uvE = uvs[(w<<4)+14], uvF = uvs[(w<<4)+15];
  int j0 = jg * 256 + 4 * lane;
  float4 wh2v = *(const float4*)(Wh2 + b * N_ + j0);
  float b2c0 = exp2f(-0.8f * wh2v.x), b2c1 = exp2f(-0.8f * wh2v.y);
  float b2c2 = exp2f(-0.8f * wh2v.z), b2c3 = exp2f(-0.8f * wh2v.w);
  const int4* ap = (const int4*)(adj + ((size_t)(b * N_ + i0)) * N_ + jg * 256);
  const size_t rs = N_ / 4;
  int qsel = lane & 3, rsel = lane >> 2;
  unsigned long long wreg = 0;
  float den0 = 0.f, den1 = 0.f, den2 = 0.f, den3 = 0.f;
  int4 r0 = ap[0 * rs + lane], r1 = ap[1 * rs + lane];
  int4 r2 = ap[2 * rs + lane], r3 = ap[3 * rs + lane];
  int4 r4 = ap[4 * rs + lane], r5 = ap[5 * rs + lane];
  int4 r6 = ap[6 * rs + lane], r7 = ap[7 * rs + lane];
  K3_PROC(r0, uv0, 0);  r0 = ap[8 * rs + lane];
  K3_PROC(r1, uv1, 1);  r1 = ap[9 * rs + lane];
  K3_PROC(r2, uv2, 2);  r2 = ap[10 * rs + lane];
  K3_PROC(r3, uv3, 3);  r3 = ap[11 * rs + lane];
  K3_PROC(r4, uv4, 4);  r4 = ap[12 * rs + lane];
  K3_PROC(r5, uv5, 5);  r5 = ap[13 * rs + lane];
  K3_PROC(r6, uv6, 6);  r6 = ap[14 * rs + lane];
  K3_PROC(r7, uv7, 7);  r7 = ap[15 * rs + lane];
  K3_PROC(r0, uv8, 8);  K3_PROC(r1, uv9, 9);  K3_PROC(r2, uvA, 10); K3_PROC(r3, uvB, 11);
  K3_PROC(r4, uvC, 12); K3_PROC(r5, uvD, 13); K3_PROC(r6, uvE, 14); K3_PROC(r7, uvF, 15);
  maskQ[((((size_t)b * 8 + jg) * 2048 + i0 + rsel) << 2) + qsel] = wreg;
  red[w][(lane << 2) + 0] = den0;
  red[w][(lane << 2) + 1] = den1;
  red[w][(lane << 2) + 2] = den2;
  red[w][(lane << 2) + 3] = den3;
  __syncthreads();
  float dsum = red[0][tid] + red[1][tid] + red[2][tid] + red[3][tid];
  dp[(size_t)ic * (B_ * N_) + b * N_ + jg * 256 + tid] = dsum;
  // fused k3e: last block per (b,jg) reduces 32 partials -> ab
  __threadfence();
  if (tid == 0) tickS = atomicAdd(cnt + b * 8 + jg, 1);
  __syncthreads();
  if (tickS == 31) {
    __threadfence();
    int j = jg * 256 + tid;
    float den = 0.f;
    #pragma unroll
    for (int p = 0; p < 32; ++p) den += dp[(size_t)p * (B_ * N_) + b * N_ + j];
    float inv = 1.0f / fmaxf(den, 1e-37f);
    float B4 = exp2f(-0.8f * Wh2[b * N_ + j]) * inv;
    ab[b * N_ + j] = make_float2(inv, B4);
  }
}

// K4: h_prime = elu(P @ WhT). 512 thr = 4 i-strips x 2 k-halves. fp16 MFMA.
__global__ __launch_bounds__(512) void k4_mfma(
    const unsigned long long* __restrict__ maskQ, const float* __restrict__ Wh1,
    const float2* __restrict__ ab, const unsigned short* __restrict__ WhbT,
    float* __restrict__ out) {
  int ib = blockIdx.x, b = blockIdx.y;   // ib in [0,32): 64 i-rows
  int tid = threadIdx.x, lane = tid & 63;
  int w = __builtin_amdgcn_readfirstlane(tid >> 6);
  int iw = w & 3, kh = w >> 2;
  extern __shared__ __align__(16) unsigned char smem[];  // 49152 B
  unsigned char* bt0 = smem;                   // 16 KB: k-half 0 [64 o][128 j] f16
  unsigned char* bt1 = smem + 16384;           // 16 KB: k-half 1
  float2* abL = (float2*)(smem + 32768);       // 16 KB
  {
    const float4* src = (const float4*)(ab + b * N_);
    ((float4*)abL)[tid] = src[tid];
    ((float4*)abL)[tid + 512] = src[tid + 512];
  }
  int l15 = lane & 15, lg = lane >> 4;
  int i0 = (ib << 6) + (iw << 4);
  int i = i0 + l15;
  float w1 = Wh1[b * N_ + i];
  float u = exp2f(w1), v = exp2f(0.2f * w1);
  f32x4_t acc[4];
  #pragma unroll
  for (int of = 0; of < 4; ++of) acc[of] = {0.f, 0.f, 0.f, 0.f};
  const unsigned short* wsrc = WhbT + (size_t)b * 64 * N_;
  unsigned char* mybt = kh ? bt1 : bt0;
  const unsigned long long* mbase = maskQ + (size_t)b * 8 * 2048 * 4;
  for (int rr = 0; rr < 8; ++rr) {
    __syncthreads();
    #pragma unroll
    for (int qq = 0; qq < 4; ++qq) {
      int slot = (qq << 9) + tid;          // [0,2048)
      int half = slot >> 10, rem = slot & 1023;
      int o = rem >> 4, s5 = rem & 15;
      int jb = half * 1024 + rr * 128 + s5 * 8;
      uint4 vv = *(const uint4*)(wsrc + (size_t)o * N_ + jb);
      *(uint4*)((half ? bt1 : bt0) + o * 256 + ((s5 * 16) ^ ((o & 7) << 4))) = vv;
    }
    __syncthreads();
    int tg = kh * 8 + rr;                  // tile index 0..15
    int jg = tg >> 1, r2 = tg & 1;
    const uint4* qp = (const uint4*)(mbase + (((size_t)jg * 2048 + i) << 2));
    uint4 q0 = qp[0], q1 = qp[1];
    unsigned long long Wq[4];
    Wq[0] = ((unsigned long long)q0.y << 32) | q0.x;
    Wq[1] = ((unsigned long long)q0.w << 32) | q0.z;
    Wq[2] = ((unsigned long long)q1.y << 32) | q1.x;
    Wq[3] = ((unsigned long long)q1.w << 32) | q1.z;
    #pragma unroll
    for (int jt2 = 0; jt2 < 2; ++jt2) {
      #pragma unroll
      for (int s = 0; s < 2; ++s) {
        int jloc = jt2 * 64 + s * 32 + lg * 8;
        int jfull = kh * 1024 + rr * 128 + jloc;
        int tbase = r2 * 32 + jt2 * 16 + s * 8 + lg * 2;
        unsigned m[4];
        #pragma unroll
        for (int k2 = 0; k2 < 4; ++k2)
          m[k2] = (unsigned)(Wq[k2] >> tbase) & 3u;
        UH A;
        #pragma unroll
        for (int p2 = 0; p2 < 4; ++p2) {
          float2 aA = abL[jfull + 2 * p2];
          float2 aB = abL[jfull + 2 * p2 + 1];
          int e0 = 2 * p2, e1 = 2 * p2 + 1;
          float plo = fmaxf(u * aA.x, v * aA.y);
          float phi = fmaxf(u * aB.x, v * aB.y);
          plo = (m[e0 & 3] & (1u << (e0 >> 2))) ? plo : 0.f;
          phi = (m[e1 & 3] & (1u << (e1 >> 2))) ? phi : 0.f;
          A.u[p2] = pkh(plo, phi);
        }
        int boff = jt2 * 128 + s * 64 + lg * 16;
        #pragma unroll
        for (int of = 0; of < 4; ++of) {
          int o = (of << 4) + l15;
          half8_t bv = *(const half8_t*)(mybt + o * 256 + (boff ^ ((o & 7) << 4)));
          acc[of] = __builtin_amdgcn_mfma_f32_16x16x32_f16(A.s, bv, acc[of], 0, 0, 0);
        }
      }
    }
  }
  __syncthreads();
  float* fred = (float*)bt0;
  if (kh == 1) {
    #pragma unroll
    for (int of = 0; of < 4; ++of)
      *(f32x4_t*)(fred + (((iw << 6) + lane) << 4) + (of << 2)) = acc[of];
  }
  __syncthreads();
  if (kh == 0) {
    #pragma unroll
    for (int of = 0; of < 4; ++of) {
      f32x4_t oth = *(const f32x4_t*)(fred + (((iw << 6) + lane) << 4) + (of << 2));
      #pragma unroll
      for (int q = 0; q < 4; ++q) {
        float xv = acc[of][q] + oth[q];
        xv = xv > 0.f ? xv : (__expf(xv) - 1.f);
        out[((size_t)(b * N_ + i0 + (lg << 2) + q)) * 64 + (of << 4) + l15] = xv;
      }
    }
  }
}

extern "C" void kernel_launch(void* const* d_in, const int* in_sizes, int n_in,
                              void* d_out, int out_size, void* d_ws, size_t ws_size,
                              hipStream_t stream) {
  const float* state = (const float*)d_in[0];
  const float* h     = (const float*)d_in[1];
  const int*   adj   = (const int*)d_in[2];
  const float* Wpw   = (const float*)d_in[3];
  const float* Wpb   = (const float*)d_in[4];
  const float* av    = (const float*)d_in[5];
  float* out = (float*)d_out;
  char* ws = (char*)d_ws;
  unsigned short* Wb = (unsigned short*)(ws + OFF_WB);
  float* Wa1  = (float*)(ws + OFF_WA1);
  float* Wa2  = (float*)(ws + OFF_WA2);
  float* Wh1  = (float*)(ws + OFF_WH1);
  float* Wh2  = (float*)(ws + OFF_WH2);
  float2* ab  = (float2*)(ws + OFF_AB);
  int*   cnt  = (int*)(ws + OFF_CNT);
  float* dp   = (float*)(ws + OFF_DP);
  unsigned short* WhbT = (unsigned short*)(ws + OFF_WHBT);
  unsigned long long* maskQ = (unsigned long long*)(ws + OFF_MASK);

  hipMemsetAsync(cnt, 0, 256, stream);
  hipLaunchKernelGGL(k1_hyperw, dim3(16, 8), dim3(256), 0, stream,
                     state, Wpw, Wpb, av, Wb, Wa1, Wa2);
  hipLaunchKernelGGL(k2_wh, dim3(32, 8), dim3(256), 0, stream,
                     h, Wb, Wa1, Wa2, Wh1, Wh2, WhbT);
  hipLaunchKernelGGL(k3_mask, dim3(8, 32, 8), dim3(256), 0, stream,
                     adj, Wh1, Wh2, dp, maskQ, cnt, ab);
  hipLaunchKernelGGL(k4_mfma, dim3(32, 8), dim3(512), 49152, stream,
                     maskQ, Wh1, ab, WhbT, out);
}

// Round 10
// 68.500 us; speedup vs baseline: 3.9176x; 3.9176x over previous
//
#include <hip/hip_runtime.h>
#include <hip/hip_bf16.h>
#include <hip/hip_fp16.h>

#define B_ 8
#define N_ 2048
#define ALPHA_ 0.2f
#define LOG2E_ 1.44269504088896f

// Workspace offsets (~8.7 MB)
#define OFF_WB    0u         // 65536  : Wb f16 [B][64 o][64 i]
#define OFF_WA1   65536u     // 2048   : Wa1 f32 [B][64]
#define OFF_WA2   67584u     // 2048   : Wa2 f32 [B][64]
#define OFF_WH1   69632u     // 65536  : wh1 [B][N] f32 (log2e-scaled)
#define OFF_WH2   135168u    // 65536  : wh2 [B][N] f32 (log2e-scaled)
#define OFF_AB    200704u    // 131072 : float2 [B][N] = (A4=1/den, B4)
#define OFF_DP    331776u    // 2097152: den partials f32 [32][B][N]
#define OFF_WHBT  2428928u   // 2097152: WhbT f16 [B][64 o][N]
#define OFF_MASK  4526080u   // 4194304: maskQ u64 [B][8 jg][N i][4 q]
                             //   bit t of (b,jg,i,q) = adj[b][i][jg*256+4t+q] > 0

typedef _Float16 half8_t __attribute__((ext_vector_type(8)));
typedef float f32x4_t __attribute__((ext_vector_type(4)));
union UH { unsigned u[4]; half8_t s; };

__device__ __forceinline__ unsigned pkh(float a, float b) {
  __half2 h = __floats2half2_rn(a, b);
  return *(unsigned*)&h;
}

// K1: W row r=(i,o): W=|state.Wp_w[r]+b|; emit Wb f16 [o][i], Wa1, Wa2
__global__ __launch_bounds__(256) void k1_hyperw(
    const float* __restrict__ state, const float* __restrict__ Wpw,
    const float* __restrict__ Wpb, const float* __restrict__ av,
    unsigned short* __restrict__ Wb, float* __restrict__ Wa1,
    float* __restrict__ Wa2) {
  int b = blockIdx.y;
  int r = blockIdx.x * 256 + threadIdx.x;
  int lane = threadIdx.x & 63;
  int i = r >> 6, o = r & 63;
  __shared__ float st[128];
  if (threadIdx.x < 128) st[threadIdx.x] = state[b * 128 + threadIdx.x];
  __syncthreads();
  float acc = Wpb[r];
  const float4* wp = (const float4*)(Wpw + (size_t)r * 128);
  #pragma unroll 8
  for (int hh = 0; hh < 32; ++hh) {
    float4 v = wp[hh];
    acc += st[hh*4]*v.x + st[hh*4+1]*v.y + st[hh*4+2]*v.z + st[hh*4+3]*v.w;
  }
  float wv = fabsf(acc);
  __half hw = __float2half(wv);
  Wb[b * 4096 + o * 64 + i] = *(unsigned short*)&hw;
  float p1 = wv * av[lane];
  float p2 = wv * av[64 + lane];
  #pragma unroll
  for (int off = 32; off > 0; off >>= 1) {
    p1 += __shfl_xor(p1, off);
    p2 += __shfl_xor(p2, off);
  }
  if (lane == 0) { Wa1[b * 64 + i] = p1; Wa2[b * 64 + i] = p2; }
}

// K2: WhbT via f16 MFMA (h @ W); wh1/wh2 via f32 dots — no LDS/barriers
__global__ __launch_bounds__(256) void k2_wh(
    const float* __restrict__ h, const unsigned short* __restrict__ Wb,
    const float* __restrict__ Wa1, const float* __restrict__ Wa2,
    float* __restrict__ Wh1, float* __restrict__ Wh2,
    unsigned short* __restrict__ WhbT) {
  int b = blockIdx.y;
  int tid = threadIdx.x, lane = tid & 63;
  int w = tid >> 6;
  int n0 = blockIdx.x * 64 + w * 16;
  int l15 = lane & 15, kg = lane >> 4;
  int row = n0 + l15;
  const float* hrow = h + (((size_t)b * N_ + row) << 6);
  float4 ha0 = *(const float4*)(hrow + kg * 8);
  float4 ha1 = *(const float4*)(hrow + kg * 8 + 4);
  float4 hb0 = *(const float4*)(hrow + 32 + kg * 8);
  float4 hb1 = *(const float4*)(hrow + 32 + kg * 8 + 4);
  const float* wa1 = Wa1 + b * 64;
  const float* wa2 = Wa2 + b * 64;
  float4 A0 = *(const float4*)(wa1 + kg * 8),      A1 = *(const float4*)(wa1 + kg * 8 + 4);
  float4 A2 = *(const float4*)(wa1 + 32 + kg * 8), A3 = *(const float4*)(wa1 + 32 + kg * 8 + 4);
  float4 C0 = *(const float4*)(wa2 + kg * 8),      C1 = *(const float4*)(wa2 + kg * 8 + 4);
  float4 C2 = *(const float4*)(wa2 + 32 + kg * 8), C3 = *(const float4*)(wa2 + 32 + kg * 8 + 4);
  float v1 = ha0.x*A0.x + ha0.y*A0.y + ha0.z*A0.z + ha0.w*A0.w
           + ha1.x*A1.x + ha1.y*A1.y + ha1.z*A1.z + ha1.w*A1.w
           + hb0.x*A2.x + hb0.y*A2.y + hb0.z*A2.z + hb0.w*A2.w
           + hb1.x*A3.x + hb1.y*A3.y + hb1.z*A3.z + hb1.w*A3.w;
  float v2 = ha0.x*C0.x + ha0.y*C0.y + ha0.z*C0.z + ha0.w*C0.w
           + ha1.x*C1.x + ha1.y*C1.y + ha1.z*C1.z + ha1.w*C1.w
           + hb0.x*C2.x + hb0.y*C2.y + hb0.z*C2.z + hb0.w*C2.w
           + hb1.x*C3.x + hb1.y*C3.y + hb1.z*C3.z + hb1.w*C3.w;
  v1 += __shfl_xor(v1, 16); v1 += __shfl_xor(v1, 32);
  v2 += __shfl_xor(v2, 16); v2 += __shfl_xor(v2, 32);
  if (lane < 16) {
    Wh1[b * N_ + row] = v1 * LOG2E_;
    Wh2[b * N_ + row] = v2 * LOG2E_;
  }
  UH ua, ub;
  ua.u[0] = pkh(ha0.x, ha0.y); ua.u[1] = pkh(ha0.z, ha0.w);
  ua.u[2] = pkh(ha1.x, ha1.y); ua.u[3] = pkh(ha1.z, ha1.w);
  ub.u[0] = pkh(hb0.x, hb0.y); ub.u[1] = pkh(hb0.z, hb0.w);
  ub.u[2] = pkh(hb1.x, hb1.y); ub.u[3] = pkh(hb1.z, hb1.w);
  const unsigned short* wbb = Wb + b * 4096;
  f32x4_t acc[4];
  #pragma unroll
  for (int of = 0; of < 4; ++of) acc[of] = {0.f, 0.f, 0.f, 0.f};
  #pragma unroll
  for (int of = 0; of < 4; ++of) {
    int o = of * 16 + l15;
    half8_t b0 = *(const half8_t*)(wbb + o * 64 + kg * 8);
    half8_t b1 = *(const half8_t*)(wbb + o * 64 + 32 + kg * 8);
    acc[of] = __builtin_amdgcn_mfma_f32_16x16x32_f16(ua.s, b0, acc[of], 0, 0, 0);
    acc[of] = __builtin_amdgcn_mfma_f32_16x16x32_f16(ub.s, b1, acc[of], 0, 0, 0);
  }
  int nb = n0 + (kg << 2);
  #pragma unroll
  for (int of = 0; of < 4; ++of) {
    int o = of * 16 + l15;
    uint2 pk;
    pk.x = pkh(acc[of][0], acc[of][1]);
    pk.y = pkh(acc[of][2], acc[of][3]);
    *(uint2*)(WhbT + ((size_t)(b * 64 + o)) * N_ + nb) = pk;
  }
}

// K3: pack ballots + exp-free den accumulation. Wave: 16 rows x 256 j.
#define K3_PROC(VV, UVV, II)                                                 \
  do {                                                                       \
    bool p0 = (VV).x > 0, p1 = (VV).y > 0, p2 = (VV).z > 0, p3 = (VV).w > 0; \
    unsigned long long b0 = __ballot(p0), b1 = __ballot(p1);                 \
    unsigned long long b2 = __ballot(p2), b3 = __ballot(p3);                 \
    unsigned long long bsel = qsel == 0 ? b0 : qsel == 1 ? b1                \
                            : qsel == 2 ? b2 : b3;                           \
    wreg = (rsel == (II)) ? bsel : wreg;                                     \
    den0 += p0 ? fmaxf((UVV).x, (UVV).y * b2c0) : 0.f;                       \
    den1 += p1 ? fmaxf((UVV).x, (UVV).y * b2c1) : 0.f;                       \
    den2 += p2 ? fmaxf((UVV).x, (UVV).y * b2c2) : 0.f;                       \
    den3 += p3 ? fmaxf((UVV).x, (UVV).y * b2c3) : 0.f;                       \
  } while (0)

__global__ __launch_bounds__(256) void k3_mask(
    const int* __restrict__ adj, const float* __restrict__ Wh1,
    const float* __restrict__ Wh2, float* __restrict__ dp,
    unsigned long long* __restrict__ maskQ) {
  int jg = blockIdx.x, ic = blockIdx.y, b = blockIdx.z;  // 8 x 32 x 8
  int tid = threadIdx.x, lane = tid & 63, w = tid >> 6;
  int i0 = ic * 64 + w * 16;
  __shared__ float2 uvs[64];
  __shared__ float red[4][256];
  if (tid < 64) {
    float w1v = Wh1[b * N_ + ic * 64 + tid];
    uvs[tid] = make_float2(exp2f(w1v), exp2f(0.2f * w1v));
  }
  __syncthreads();
  float2 uv0 = uvs[(w<<4)+0],  uv1 = uvs[(w<<4)+1],  uv2 = uvs[(w<<4)+2],  uv3 = uvs[(w<<4)+3];
  float2 uv4 = uvs[(w<<4)+4],  uv5 = uvs[(w<<4)+5],  uv6 = uvs[(w<<4)+6],  uv7 = uvs[(w<<4)+7];
  float2 uv8 = uvs[(w<<4)+8],  uv9 = uvs[(w<<4)+9],  uvA = uvs[(w<<4)+10], uvB = uvs[(w<<4)+11];
  float2 uvC = uvs[(w<<4)+12], uvD = uvs[(w<<4)+13], uvE = uvs[(w<<4)+14], uvF = uvs[(w<<4)+15];
  int j0 = jg * 256 + 4 * lane;
  float4 wh2v = *(const float4*)(Wh2 + b * N_ + j0);
  float b2c0 = exp2f(-0.8f * wh2v.x), b2c1 = exp2f(-0.8f * wh2v.y);
  float b2c2 = exp2f(-0.8f * wh2v.z), b2c3 = exp2f(-0.8f * wh2v.w);
  const int4* ap = (const int4*)(adj + ((size_t)(b * N_ + i0)) * N_ + jg * 256);
  const size_t rs = N_ / 4;
  int qsel = lane & 3, rsel = lane >> 2;
  unsigned long long wreg = 0;
  float den0 = 0.f, den1 = 0.f, den2 = 0.f, den3 = 0.f;
  int4 r0 = ap[0 * rs + lane], r1 = ap[1 * rs + lane];
  int4 r2 = ap[2 * rs + lane], r3 = ap[3 * rs + lane];
  int4 r4 = ap[4 * rs + lane], r5 = ap[5 * rs + lane];
  int4 r6 = ap[6 * rs + lane], r7 = ap[7 * rs + lane];
  K3_PROC(r0, uv0, 0);  r0 = ap[8 * rs + lane];
  K3_PROC(r1, uv1, 1);  r1 = ap[9 * rs + lane];
  K3_PROC(r2, uv2, 2);  r2 = ap[10 * rs + lane];
  K3_PROC(r3, uv3, 3);  r3 = ap[11 * rs + lane];
  K3_PROC(r4, uv4, 4);  r4 = ap[12 * rs + lane];
  K3_PROC(r5, uv5, 5);  r5 = ap[13 * rs + lane];
  K3_PROC(r6, uv6, 6);  r6 = ap[14 * rs + lane];
  K3_PROC(r7, uv7, 7);  r7 = ap[15 * rs + lane];
  K3_PROC(r0, uv8, 8);  K3_PROC(r1, uv9, 9);  K3_PROC(r2, uvA, 10); K3_PROC(r3, uvB, 11);
  K3_PROC(r4, uvC, 12); K3_PROC(r5, uvD, 13); K3_PROC(r6, uvE, 14); K3_PROC(r7, uvF, 15);
  maskQ[((((size_t)b * 8 + jg) * 2048 + i0 + rsel) << 2) + qsel] = wreg;
  red[w][(lane << 2) + 0] = den0;
  red[w][(lane << 2) + 1] = den1;
  red[w][(lane << 2) + 2] = den2;
  red[w][(lane << 2) + 3] = den3;
  __syncthreads();
  float dsum = red[0][tid] + red[1][tid] + red[2][tid] + red[3][tid];
  dp[(size_t)ic * (B_ * N_) + b * N_ + jg * 256 + tid] = dsum;
}

// K3e: ab[j] = (A4 = 1/den, B4 = 2^(-0.8 wh2)/den)
__global__ __launch_bounds__(256) void k3e_ab(
    const float* __restrict__ dp, const float* __restrict__ Wh2,
    float2* __restrict__ ab) {
  int x = blockIdx.x * 256 + threadIdx.x;  // [0, B*N)
  float den = 0.f;
  #pragma unroll
  for (int p = 0; p < 32; ++p) den += dp[(size_t)p * (B_ * N_) + x];
  float inv = 1.0f / fmaxf(den, 1e-37f);
  float B4 = exp2f(-0.8f * Wh2[x]) * inv;
  ab[x] = make_float2(inv, B4);
}

// K4: h_prime = elu(P @ WhT). 512 thr = 4 i-strips x 2 k-halves. fp16 MFMA.
__global__ __launch_bounds__(512) void k4_mfma(
    const unsigned long long* __restrict__ maskQ, const float* __restrict__ Wh1,
    const float2* __restrict__ ab, const unsigned short* __restrict__ WhbT,
    float* __restrict__ out) {
  int ib = blockIdx.x, b = blockIdx.y;   // ib in [0,32): 64 i-rows
  int tid = threadIdx.x, lane = tid & 63;
  int w = __builtin_amdgcn_readfirstlane(tid >> 6);
  int iw = w & 3, kh = w >> 2;
  extern __shared__ __align__(16) unsigned char smem[];  // 49152 B
  unsigned char* bt0 = smem;                   // 16 KB: k-half 0 [64 o][128 j] f16
  unsigned char* bt1 = smem + 16384;           // 16 KB: k-half 1
  float2* abL = (float2*)(smem + 32768);       // 16 KB
  {
    const float4* src = (const float4*)(ab + b * N_);
    ((float4*)abL)[tid] = src[tid];
    ((float4*)abL)[tid + 512] = src[tid + 512];
  }
  int l15 = lane & 15, lg = lane >> 4;
  int i0 = (ib << 6) + (iw << 4);
  int i = i0 + l15;
  float w1 = Wh1[b * N_ + i];
  float u = exp2f(w1), v = exp2f(0.2f * w1);
  f32x4_t acc[4];
  #pragma unroll
  for (int of = 0; of < 4; ++of) acc[of] = {0.f, 0.f, 0.f, 0.f};
  const unsigned short* wsrc = WhbT + (size_t)b * 64 * N_;
  unsigned char* mybt = kh ? bt1 : bt0;
  const unsigned long long* mbase = maskQ + (size_t)b * 8 * 2048 * 4;
  for (int rr = 0; rr < 8; ++rr) {
    __syncthreads();
    #pragma unroll
    for (int qq = 0; qq < 4; ++qq) {
      int slot = (qq << 9) + tid;          // [0,2048)
      int half = slot >> 10, rem = slot & 1023;
      int o = rem >> 4, s5 = rem & 15;
      int jb = half * 1024 + rr * 128 + s5 * 8;
      uint4 vv = *(const uint4*)(wsrc + (size_t)o * N_ + jb);
      *(uint4*)((half ? bt1 : bt0) + o * 256 + ((s5 * 16) ^ ((o & 7) << 4))) = vv;
    }
    __syncthreads();
    int tg = kh * 8 + rr;                  // tile index 0..15
    int jg = tg >> 1, r2 = tg & 1;
    const uint4* qp = (const uint4*)(mbase + (((size_t)jg * 2048 + i) << 2));
    uint4 q0 = qp[0], q1 = qp[1];
    unsigned long long Wq[4];
    Wq[0] = ((unsigned long long)q0.y << 32) | q0.x;
    Wq[1] = ((unsigned long long)q0.w << 32) | q0.z;
    Wq[2] = ((unsigned long long)q1.y << 32) | q1.x;
    Wq[3] = ((unsigned long long)q1.w << 32) | q1.z;
    #pragma unroll
    for (int jt2 = 0; jt2 < 2; ++jt2) {
      #pragma unroll
      for (int s = 0; s < 2; ++s) {
        int jfull = kh * 1024 + rr * 128 + jt2 * 64 + s * 32 + lg * 8;
        int tbase = r2 * 32 + jt2 * 16 + s * 8 + lg * 2;
        unsigned m[4];
        #pragma unroll
        for (int k2 = 0; k2 < 4; ++k2)
          m[k2] = (unsigned)(Wq[k2] >> tbase) & 3u;
        UH A;
        #pragma unroll
        for (int p2 = 0; p2 < 4; ++p2) {
          float2 aA = abL[jfull + 2 * p2];
          float2 aB = abL[jfull + 2 * p2 + 1];
          int e0 = 2 * p2, e1 = 2 * p2 + 1;
          float plo = fmaxf(u * aA.x, v * aA.y);
          float phi = fmaxf(u * aB.x, v * aB.y);
          plo = (m[e0 & 3] & (1u << (e0 >> 2))) ? plo : 0.f;
          phi = (m[e1 & 3] & (1u << (e1 >> 2))) ? phi : 0.f;
          A.u[p2] = pkh(plo, phi);
        }
        int boff = jt2 * 128 + s * 64 + lg * 16;
        #pragma unroll
        for (int of = 0; of < 4; ++of) {
          int o = (of << 4) + l15;
          half8_t bv = *(const half8_t*)(mybt + o * 256 + (boff ^ ((o & 7) << 4)));
          acc[of] = __builtin_amdgcn_mfma_f32_16x16x32_f16(A.s, bv, acc[of], 0, 0, 0);
        }
      }
    }
  }
  __syncthreads();
  float* fred = (float*)bt0;
  if (kh == 1) {
    #pragma unroll
    for (int of = 0; of < 4; ++of)
      *(f32x4_t*)(fred + (((iw << 6) + lane) << 4) + (of << 2)) = acc[of];
  }
  __syncthreads();
  if (kh == 0) {
    #pragma unroll
    for (int of = 0; of < 4; ++of) {
      f32x4_t oth = *(const f32x4_t*)(fred + (((iw << 6) + lane) << 4) + (of << 2));
      #pragma unroll
      for (int q = 0; q < 4; ++q) {
        float xv = acc[of][q] + oth[q];
        xv = xv > 0.f ? xv : (__expf(xv) - 1.f);
        out[((size_t)(b * N_ + i0 + (lg << 2) + q)) * 64 + (of << 4) + l15] = xv;
      }
    }
  }
}

extern "C" void kernel_launch(void* const* d_in, const int* in_sizes, int n_in,
                              void* d_out, int out_size, void* d_ws, size_t ws_size,
                              hipStream_t stream) {
  const float* state = (const float*)d_in[0];
  const float* h     = (const float*)d_in[1];
  const int*   adj   = (const int*)d_in[2];
  const float* Wpw   = (const float*)d_in[3];
  const float* Wpb   = (const float*)d_in[4];
  const float* av    = (const float*)d_in[5];
  float* out = (float*)d_out;
  char* ws = (char*)d_ws;
  unsigned short* Wb = (unsigned short*)(ws + OFF_WB);
  float* Wa1  = (float*)(ws + OFF_WA1);
  float* Wa2  = (float*)(ws + OFF_WA2);
  float* Wh1  = (float*)(ws + OFF_WH1);
  float* Wh2  = (float*)(ws + OFF_WH2);
  float2* ab  = (float2*)(ws + OFF_AB);
  float* dp   = (float*)(ws + OFF_DP);
  unsigned short* WhbT = (unsigned short*)(ws + OFF_WHBT);
  unsigned long long* maskQ = (unsigned long long*)(ws + OFF_MASK);

  hipLaunchKernelGGL(k1_hyperw, dim3(16, 8), dim3(256), 0, stream,
                     state, Wpw, Wpb, av, Wb, Wa1, Wa2);
  hipLaunchKernelGGL(k2_wh, dim3(32, 8), dim3(256), 0, stream,
                     h, Wb, Wa1, Wa2, Wh1, Wh2, WhbT);
  hipLaunchKernelGGL(k3_mask, dim3(8, 32, 8), dim3(256), 0, stream,
                     adj, Wh1, Wh2, dp, maskQ);
  hipLaunchKernelGGL(k3e_ab, dim3(64), dim3(256), 0, stream, dp, Wh2, ab);
  hipLaunchKernelGGL(k4_mfma, dim3(32, 8), dim3(512), 49152, stream,
                     maskQ, Wh1, ab, WhbT, out);
}

// Round 11
// 62.624 us; speedup vs baseline: 4.2852x; 1.0938x over previous
//
#include <hip/hip_runtime.h>
#include <hip/hip_bf16.h>
#include <hip/hip_fp16.h>

#define B_ 8
#define N_ 2048
#define ALPHA_ 0.2f
#define LOG2E_ 1.44269504088896f

// Workspace offsets (~6.6 MB)
#define OFF_WB    0u         // 65536  : Wb f16 [B][64 o][64 i]
#define OFF_WA1   65536u     // 2048   : Wa1 f32 [B][64]
#define OFF_WA2   67584u     // 2048   : Wa2 f32 [B][64]
#define OFF_WH1   69632u     // 65536  : wh1 [B][N] f32 (log2e-scaled)
#define OFF_WH2   135168u    // 65536  : wh2 [B][N] f32 (log2e-scaled)
#define OFF_DEN   200704u    // 65536  : den [B][N] f32 (atomic-accumulated)
#define OFF_WHBT  266240u    // 2097152: WhbT f16 [B][64 o][N]
#define OFF_MASK  2363392u   // 4194304: maskQ u64 [B][8 jg][N i][4 q]
                             //   bit t of (b,jg,i,q) = adj[b][i][jg*256+4t+q] > 0

typedef _Float16 half8_t __attribute__((ext_vector_type(8)));
typedef float f32x4_t __attribute__((ext_vector_type(4)));
union UH { unsigned u[4]; half8_t s; };

__device__ __forceinline__ unsigned pkh(float a, float b) {   // f16 pair
  __half2 h = __floats2half2_rn(a, b);
  return *(unsigned*)&h;
}
__device__ __forceinline__ unsigned pk2(float lo, float hi) { // bf16 pair
  return ((__float_as_uint(hi) + 0x8000u) & 0xFFFF0000u) |
         ((__float_as_uint(lo) + 0x8000u) >> 16);
}

// K1: W row r=(i,o): W=|state.Wp_w[r]+b|; emit Wb f16 [o][i], Wa1, Wa2
__global__ __launch_bounds__(256) void k1_hyperw(
    const float* __restrict__ state, const float* __restrict__ Wpw,
    const float* __restrict__ Wpb, const float* __restrict__ av,
    unsigned short* __restrict__ Wb, float* __restrict__ Wa1,
    float* __restrict__ Wa2) {
  int b = blockIdx.y;
  int r = blockIdx.x * 256 + threadIdx.x;
  int lane = threadIdx.x & 63;
  int i = r >> 6, o = r & 63;
  __shared__ float st[128];
  if (threadIdx.x < 128) st[threadIdx.x] = state[b * 128 + threadIdx.x];
  __syncthreads();
  float acc = Wpb[r];
  const float4* wp = (const float4*)(Wpw + (size_t)r * 128);
  #pragma unroll 8
  for (int hh = 0; hh < 32; ++hh) {
    float4 v = wp[hh];
    acc += st[hh*4]*v.x + st[hh*4+1]*v.y + st[hh*4+2]*v.z + st[hh*4+3]*v.w;
  }
  float wv = fabsf(acc);
  __half hw = __float2half(wv);
  Wb[b * 4096 + o * 64 + i] = *(unsigned short*)&hw;
  float p1 = wv * av[lane];
  float p2 = wv * av[64 + lane];
  #pragma unroll
  for (int off = 32; off > 0; off >>= 1) {
    p1 += __shfl_xor(p1, off);
    p2 += __shfl_xor(p2, off);
  }
  if (lane == 0) { Wa1[b * 64 + i] = p1; Wa2[b * 64 + i] = p2; }
}

// K2: WhbT via f16 MFMA (h @ W); wh1/wh2 via f32 dots — no LDS/barriers
__global__ __launch_bounds__(256) void k2_wh(
    const float* __restrict__ h, const unsigned short* __restrict__ Wb,
    const float* __restrict__ Wa1, const float* __restrict__ Wa2,
    float* __restrict__ Wh1, float* __restrict__ Wh2,
    unsigned short* __restrict__ WhbT) {
  int b = blockIdx.y;
  int tid = threadIdx.x, lane = tid & 63;
  int w = tid >> 6;
  int n0 = blockIdx.x * 64 + w * 16;
  int l15 = lane & 15, kg = lane >> 4;
  int row = n0 + l15;
  const float* hrow = h + (((size_t)b * N_ + row) << 6);
  float4 ha0 = *(const float4*)(hrow + kg * 8);
  float4 ha1 = *(const float4*)(hrow + kg * 8 + 4);
  float4 hb0 = *(const float4*)(hrow + 32 + kg * 8);
  float4 hb1 = *(const float4*)(hrow + 32 + kg * 8 + 4);
  const float* wa1 = Wa1 + b * 64;
  const float* wa2 = Wa2 + b * 64;
  float4 A0 = *(const float4*)(wa1 + kg * 8),      A1 = *(const float4*)(wa1 + kg * 8 + 4);
  float4 A2 = *(const float4*)(wa1 + 32 + kg * 8), A3 = *(const float4*)(wa1 + 32 + kg * 8 + 4);
  float4 C0 = *(const float4*)(wa2 + kg * 8),      C1 = *(const float4*)(wa2 + kg * 8 + 4);
  float4 C2 = *(const float4*)(wa2 + 32 + kg * 8), C3 = *(const float4*)(wa2 + 32 + kg * 8 + 4);
  float v1 = ha0.x*A0.x + ha0.y*A0.y + ha0.z*A0.z + ha0.w*A0.w
           + ha1.x*A1.x + ha1.y*A1.y + ha1.z*A1.z + ha1.w*A1.w
           + hb0.x*A2.x + hb0.y*A2.y + hb0.z*A2.z + hb0.w*A2.w
           + hb1.x*A3.x + hb1.y*A3.y + hb1.z*A3.z + hb1.w*A3.w;
  float v2 = ha0.x*C0.x + ha0.y*C0.y + ha0.z*C0.z + ha0.w*C0.w
           + ha1.x*C1.x + ha1.y*C1.y + ha1.z*C1.z + ha1.w*C1.w
           + hb0.x*C2.x + hb0.y*C2.y + hb0.z*C2.z + hb0.w*C2.w
           + hb1.x*C3.x + hb1.y*C3.y + hb1.z*C3.z + hb1.w*C3.w;
  v1 += __shfl_xor(v1, 16); v1 += __shfl_xor(v1, 32);
  v2 += __shfl_xor(v2, 16); v2 += __shfl_xor(v2, 32);
  if (lane < 16) {
    Wh1[b * N_ + row] = v1 * LOG2E_;
    Wh2[b * N_ + row] = v2 * LOG2E_;
  }
  UH ua, ub;
  ua.u[0] = pkh(ha0.x, ha0.y); ua.u[1] = pkh(ha0.z, ha0.w);
  ua.u[2] = pkh(ha1.x, ha1.y); ua.u[3] = pkh(ha1.z, ha1.w);
  ub.u[0] = pkh(hb0.x, hb0.y); ub.u[1] = pkh(hb0.z, hb0.w);
  ub.u[2] = pkh(hb1.x, hb1.y); ub.u[3] = pkh(hb1.z, hb1.w);
  const unsigned short* wbb = Wb + b * 4096;
  f32x4_t acc[4];
  #pragma unroll
  for (int of = 0; of < 4; ++of) acc[of] = {0.f, 0.f, 0.f, 0.f};
  #pragma unroll
  for (int of = 0; of < 4; ++of) {
    int o = of * 16 + l15;
    half8_t b0 = *(const half8_t*)(wbb + o * 64 + kg * 8);
    half8_t b1 = *(const half8_t*)(wbb + o * 64 + 32 + kg * 8);
    acc[of] = __builtin_amdgcn_mfma_f32_16x16x32_f16(ua.s, b0, acc[of], 0, 0, 0);
    acc[of] = __builtin_amdgcn_mfma_f32_16x16x32_f16(ub.s, b1, acc[of], 0, 0, 0);
  }
  int nb = n0 + (kg << 2);
  #pragma unroll
  for (int of = 0; of < 4; ++of) {
    int o = of * 16 + l15;
    uint2 pk;
    pk.x = pkh(acc[of][0], acc[of][1]);
    pk.y = pkh(acc[of][2], acc[of][3]);
    *(uint2*)(WhbT + ((size_t)(b * 64 + o)) * N_ + nb) = pk;
  }
}

// K3: pack ballots + exp-free den accumulation; block-reduced den -> one
// atomicAdd per (j) per block (32 adds/address across ic blocks).
#define K3_PROC(VV, UVV, II)                                                 \
  do {                                                                       \
    bool p0 = (VV).x > 0, p1 = (VV).y > 0, p2 = (VV).z > 0, p3 = (VV).w > 0; \
    unsigned long long b0 = __ballot(p0), b1 = __ballot(p1);                 \
    unsigned long long b2 = __ballot(p2), b3 = __ballot(p3);                 \
    unsigned long long bsel = qsel == 0 ? b0 : qsel == 1 ? b1                \
                            : qsel == 2 ? b2 : b3;                           \
    wreg = (rsel == (II)) ? bsel : wreg;                                     \
    den0 += p0 ? fmaxf((UVV).x, (UVV).y * b2c0) : 0.f;                       \
    den1 += p1 ? fmaxf((UVV).x, (UVV).y * b2c1) : 0.f;                       \
    den2 += p2 ? fmaxf((UVV).x, (UVV).y * b2c2) : 0.f;                       \
    den3 += p3 ? fmaxf((UVV).x, (UVV).y * b2c3) : 0.f;                       \
  } while (0)

__global__ __launch_bounds__(256) void k3_mask(
    const int* __restrict__ adj, const float* __restrict__ Wh1,
    const float* __restrict__ Wh2, float* __restrict__ den,
    unsigned long long* __restrict__ maskQ) {
  int jg = blockIdx.x, ic = blockIdx.y, b = blockIdx.z;  // 8 x 32 x 8
  int tid = threadIdx.x, lane = tid & 63, w = tid >> 6;
  int i0 = ic * 64 + w * 16;
  __shared__ float2 uvs[64];
  __shared__ float red[4][256];
  if (tid < 64) {
    float w1v = Wh1[b * N_ + ic * 64 + tid];
    uvs[tid] = make_float2(exp2f(w1v), exp2f(0.2f * w1v));
  }
  __syncthreads();
  float2 uv0 = uvs[(w<<4)+0],  uv1 = uvs[(w<<4)+1],  uv2 = uvs[(w<<4)+2],  uv3 = uvs[(w<<4)+3];
  float2 uv4 = uvs[(w<<4)+4],  uv5 = uvs[(w<<4)+5],  uv6 = uvs[(w<<4)+6],  uv7 = uvs[(w<<4)+7];
  float2 uv8 = uvs[(w<<4)+8],  uv9 = uvs[(w<<4)+9],  uvA = uvs[(w<<4)+10], uvB = uvs[(w<<4)+11];
  float2 uvC = uvs[(w<<4)+12], uvD = uvs[(w<<4)+13], uvE = uvs[(w<<4)+14], uvF = uvs[(w<<4)+15];
  int j0 = jg * 256 + 4 * lane;
  float4 wh2v = *(const float4*)(Wh2 + b * N_ + j0);
  float b2c0 = exp2f(-0.8f * wh2v.x), b2c1 = exp2f(-0.8f * wh2v.y);
  float b2c2 = exp2f(-0.8f * wh2v.z), b2c3 = exp2f(-0.8f * wh2v.w);
  const int4* ap = (const int4*)(adj + ((size_t)(b * N_ + i0)) * N_ + jg * 256);
  const size_t rs = N_ / 4;
  int qsel = lane & 3, rsel = lane >> 2;
  unsigned long long wreg = 0;
  float den0 = 0.f, den1 = 0.f, den2 = 0.f, den3 = 0.f;
  int4 r0 = ap[0 * rs + lane], r1 = ap[1 * rs + lane];
  int4 r2 = ap[2 * rs + lane], r3 = ap[3 * rs + lane];
  int4 r4 = ap[4 * rs + lane], r5 = ap[5 * rs + lane];
  int4 r6 = ap[6 * rs + lane], r7 = ap[7 * rs + lane];
  K3_PROC(r0, uv0, 0);  r0 = ap[8 * rs + lane];
  K3_PROC(r1, uv1, 1);  r1 = ap[9 * rs + lane];
  K3_PROC(r2, uv2, 2);  r2 = ap[10 * rs + lane];
  K3_PROC(r3, uv3, 3);  r3 = ap[11 * rs + lane];
  K3_PROC(r4, uv4, 4);  r4 = ap[12 * rs + lane];
  K3_PROC(r5, uv5, 5);  r5 = ap[13 * rs + lane];
  K3_PROC(r6, uv6, 6);  r6 = ap[14 * rs + lane];
  K3_PROC(r7, uv7, 7);  r7 = ap[15 * rs + lane];
  K3_PROC(r0, uv8, 8);  K3_PROC(r1, uv9, 9);  K3_PROC(r2, uvA, 10); K3_PROC(r3, uvB, 11);
  K3_PROC(r4, uvC, 12); K3_PROC(r5, uvD, 13); K3_PROC(r6, uvE, 14); K3_PROC(r7, uvF, 15);
  maskQ[((((size_t)b * 8 + jg) * 2048 + i0 + rsel) << 2) + qsel] = wreg;
  red[w][(lane << 2) + 0] = den0;
  red[w][(lane << 2) + 1] = den1;
  red[w][(lane << 2) + 2] = den2;
  red[w][(lane << 2) + 3] = den3;
  __syncthreads();
  float dsum = red[0][tid] + red[1][tid] + red[2][tid] + red[3][tid];
  atomicAdd(den + b * N_ + jg * 256 + tid, dsum);
}

// K4: builds ab table from den, then h_prime = elu(P @ WhT). 512 thr =
// 4 i-strips x 2 k-halves. T14 async-stage (SLOAD early / SWRITE late).
__global__ __launch_bounds__(512) void k4_mfma(
    const unsigned long long* __restrict__ maskQ, const float* __restrict__ Wh1,
    const float* __restrict__ Wh2, const float* __restrict__ den,
    const unsigned short* __restrict__ WhbT, float* __restrict__ out) {
  int ib = blockIdx.x, b = blockIdx.y;   // ib in [0,32): 64 i-rows
  int tid = threadIdx.x, lane = tid & 63;
  int w = __builtin_amdgcn_readfirstlane(tid >> 6);
  int iw = w & 3, kh = w >> 2;
  extern __shared__ __align__(16) unsigned char smem[];  // 40960 B
  // [0,16384): k-half 0 tile [64 o][256 B swz]; [16384,32768): k-half 1;
  // [32768,40960): abL u32[2048] packed bf16 (lo=B4, hi=A4)
  unsigned* abL = (unsigned*)(smem + 32768);
  const unsigned short* wsrc = WhbT + (size_t)b * 64 * N_;
  int sl1 = 512 + tid, sl2 = 1024 + tid, sl3 = 1536 + tid;
  int h0 = 0, h1 = 0, h2 = 1, h3 = 1;
  int o0 = tid >> 4, o1 = (sl1 & 1023) >> 4, o2 = (sl2 & 1023) >> 4, o3 = (sl3 & 1023) >> 4;
  int s0 = tid & 15, s1 = sl1 & 15, s2 = sl2 & 15, s3 = sl3 & 15;
  uint4 sv0, sv1, sv2, sv3;
#define SLOAD(RR)                                                               \
  { sv0 = *(const uint4*)(wsrc + (size_t)o0 * N_ + h0 * 1024 + (RR) * 128 + s0 * 8); \
    sv1 = *(const uint4*)(wsrc + (size_t)o1 * N_ + h1 * 1024 + (RR) * 128 + s1 * 8); \
    sv2 = *(const uint4*)(wsrc + (size_t)o2 * N_ + h2 * 1024 + (RR) * 128 + s2 * 8); \
    sv3 = *(const uint4*)(wsrc + (size_t)o3 * N_ + h3 * 1024 + (RR) * 128 + s3 * 8); }
#define SWRITE()                                                                \
  { *(uint4*)(smem + h0 * 16384 + o0 * 256 + ((s0 * 16) ^ ((o0 & 7) << 4))) = sv0; \
    *(uint4*)(smem + h1 * 16384 + o1 * 256 + ((s1 * 16) ^ ((o1 & 7) << 4))) = sv1; \
    *(uint4*)(smem + h2 * 16384 + o2 * 256 + ((s2 * 16) ^ ((o2 & 7) << 4))) = sv2; \
    *(uint4*)(smem + h3 * 16384 + o3 * 256 + ((s3 * 16) ^ ((o3 & 7) << 4))) = sv3; }
  SLOAD(0)
  // build ab table: 4 j per thread (latency hides under SLOAD)
  #pragma unroll
  for (int q = 0; q < 4; ++q) {
    int j = (q << 9) + tid;
    float dv = den[b * N_ + j];
    float inv = 1.0f / fmaxf(dv, 1e-37f);
    float B4 = exp2f(-0.8f * Wh2[b * N_ + j]) * inv;
    abL[j] = pk2(B4, inv);
  }
  SWRITE()
  int l15 = lane & 15, lg = lane >> 4;
  int i0 = (ib << 6) + (iw << 4);
  int i = i0 + l15;
  float w1 = Wh1[b * N_ + i];
  float u = exp2f(w1), v = exp2f(0.2f * w1);
  f32x4_t acc[4];
  #pragma unroll
  for (int of = 0; of < 4; ++of) acc[of] = {0.f, 0.f, 0.f, 0.f};
  unsigned char* mybt = smem + kh * 16384;
  const unsigned long long* mbase = maskQ + (size_t)b * 8 * 2048 * 4;
  for (int rr = 0; rr < 8; ++rr) {
    __syncthreads();                 // tile rr (and abL on rr=0) visible
    if (rr < 7) SLOAD(rr + 1)        // issue next-tile globals under compute
    int tg = kh * 8 + rr;            // tile index 0..15
    int jg = tg >> 1, r2 = tg & 1;
    const uint4* qp = (const uint4*)(mbase + (((size_t)jg * 2048 + i) << 2));
    uint4 q0 = qp[0], q1 = qp[1];
    unsigned long long Wq[4];
    Wq[0] = ((unsigned long long)q0.y << 32) | q0.x;
    Wq[1] = ((unsigned long long)q0.w << 32) | q0.z;
    Wq[2] = ((unsigned long long)q1.y << 32) | q1.x;
    Wq[3] = ((unsigned long long)q1.w << 32) | q1.z;
    #pragma unroll
    for (int jt2 = 0; jt2 < 2; ++jt2) {
      #pragma unroll
      for (int s = 0; s < 2; ++s) {
        int jfull = kh * 1024 + rr * 128 + jt2 * 64 + s * 32 + lg * 8;
        int tbase = r2 * 32 + jt2 * 16 + s * 8 + lg * 2;
        unsigned m[4];
        #pragma unroll
        for (int k2 = 0; k2 < 4; ++k2)
          m[k2] = (unsigned)(Wq[k2] >> tbase) & 3u;
        const uint4* abp = (const uint4*)&abL[jfull];
        uint4 a0 = abp[0], a1 = abp[1];
        unsigned aw[8] = {a0.x, a0.y, a0.z, a0.w, a1.x, a1.y, a1.z, a1.w};
        UH A;
        #pragma unroll
        for (int p2 = 0; p2 < 4; ++p2) {
          int e0 = 2 * p2, e1 = 2 * p2 + 1;
          float A40 = __uint_as_float(aw[e0] & 0xFFFF0000u);
          float B40 = __uint_as_float(aw[e0] << 16);
          float A41 = __uint_as_float(aw[e1] & 0xFFFF0000u);
          float B41 = __uint_as_float(aw[e1] << 16);
          float plo = fmaxf(u * A40, v * B40);
          float phi = fmaxf(u * A41, v * B41);
          plo = (m[e0 & 3] & (1u << (e0 >> 2))) ? plo : 0.f;
          phi = (m[e1 & 3] & (1u << (e1 >> 2))) ? phi : 0.f;
          A.u[p2] = pkh(plo, phi);
        }
        int boff = jt2 * 128 + s * 64 + lg * 16;
        #pragma unroll
        for (int of = 0; of < 4; ++of) {
          int o = (of << 4) + l15;
          half8_t bv = *(const half8_t*)(mybt + o * 256 + (boff ^ ((o & 7) << 4)));
          acc[of] = __builtin_amdgcn_mfma_f32_16x16x32_f16(A.s, bv, acc[of], 0, 0, 0);
        }
      }
    }
    __syncthreads();                 // all waves done reading tile rr
    if (rr < 7) SWRITE()             // write next tile (waits vmcnt)
  }
  __syncthreads();
  float* fred = (float*)smem;
  if (kh == 1) {
    #pragma unroll
    for (int of = 0; of < 4; ++of)
      *(f32x4_t*)(fred + (((iw << 6) + lane) << 4) + (of << 2)) = acc[of];
  }
  __syncthreads();
  if (kh == 0) {
    #pragma unroll
    for (int of = 0; of < 4; ++of) {
      f32x4_t oth = *(const f32x4_t*)(fred + (((iw << 6) + lane) << 4) + (of << 2));
      #pragma unroll
      for (int q = 0; q < 4; ++q) {
        float xv = acc[of][q] + oth[q];
        xv = xv > 0.f ? xv : (__expf(xv) - 1.f);
        out[((size_t)(b * N_ + i0 + (lg << 2) + q)) * 64 + (of << 4) + l15] = xv;
      }
    }
  }
}

extern "C" void kernel_launch(void* const* d_in, const int* in_sizes, int n_in,
                              void* d_out, int out_size, void* d_ws, size_t ws_size,
                              hipStream_t stream) {
  const float* state = (const float*)d_in[0];
  const float* h     = (const float*)d_in[1];
  const int*   adj   = (const int*)d_in[2];
  const float* Wpw   = (const float*)d_in[3];
  const float* Wpb   = (const float*)d_in[4];
  const float* av    = (const float*)d_in[5];
  float* out = (float*)d_out;
  char* ws = (char*)d_ws;
  unsigned short* Wb = (unsigned short*)(ws + OFF_WB);
  float* Wa1  = (float*)(ws + OFF_WA1);
  float* Wa2  = (float*)(ws + OFF_WA2);
  float* Wh1  = (float*)(ws + OFF_WH1);
  float* Wh2  = (float*)(ws + OFF_WH2);
  float* den  = (float*)(ws + OFF_DEN);
  unsigned short* WhbT = (unsigned short*)(ws + OFF_WHBT);
  unsigned long long* maskQ = (unsigned long long*)(ws + OFF_MASK);

  hipMemsetAsync(den, 0, B_ * N_ * sizeof(float), stream);
  hipLaunchKernelGGL(k1_hyperw, dim3(16, 8), dim3(256), 0, stream,
                     state, Wpw, Wpb, av, Wb, Wa1, Wa2);
  hipLaunchKernelGGL(k2_wh, dim3(32, 8), dim3(256), 0, stream,
                     h, Wb, Wa1, Wa2, Wh1, Wh2, WhbT);
  hipLaunchKernelGGL(k3_mask, dim3(8, 32, 8), dim3(256), 0, stream,
                     adj, Wh1, Wh2, den, maskQ);
  hipLaunchKernelGGL(k4_mfma, dim3(32, 8), dim3(512), 40960, stream,
                     maskQ, Wh1, Wh2, den, WhbT, out);
}